// Round 2
// baseline (590.013 us; speedup 1.0000x reference)
//
#include <hip/hip_runtime.h>
#include <cstdint>
#include <cstddef>

// Problem constants (B=8,T=4,N1=1024,N2=64,D=1024,H=16,DH=64)
constexpr int CB = 8, CT = 4, CN1 = 1024, CN2 = 64, CD = 1024, CH = 16, CDH = 64;
constexpr int CBT = CB * CT;          // 32
constexpr int CNK = CN1 + 1;          // 1025
constexpr int CINNER = CH * CDH;      // 1024

// ---------- bf16 helpers (raw ushort storage) ----------
__device__ __forceinline__ unsigned short f2bf(float f) {
  union { float f; unsigned int u; } v; v.f = f;
  unsigned int u = v.u;
  u += 0x7fffu + ((u >> 16) & 1u);    // RNE
  return (unsigned short)(u >> 16);
}

// ---------- MFMA types ----------
typedef __attribute__((ext_vector_type(8))) short short8;
typedef __attribute__((ext_vector_type(8))) __bf16 bf16x8;
typedef __attribute__((ext_vector_type(4))) float floatx4;

template <typename V>
__device__ __forceinline__ auto mfma_bf16_impl(V a, V b, floatx4 c, int)
    -> decltype(__builtin_amdgcn_mfma_f32_16x16x32_bf16(a, b, c, 0, 0, 0)) {
  return __builtin_amdgcn_mfma_f32_16x16x32_bf16(a, b, c, 0, 0, 0);
}
template <typename V>
__device__ __forceinline__ floatx4 mfma_bf16_impl(V a, V b, floatx4 c, long) {
  return __builtin_amdgcn_mfma_f32_16x16x32_bf16(
      __builtin_bit_cast(bf16x8, a), __builtin_bit_cast(bf16x8, b), c, 0, 0, 0);
}
__device__ __forceinline__ floatx4 mfma_bf16(short8 a, short8 b, floatx4 c) {
  return mfma_bf16_impl(a, b, c, 0);
}

// ---------- async global->LDS (16B/lane), guarded w/ manual fallback ----------
#if __has_builtin(__builtin_amdgcn_global_load_lds)
#define HAS_GLDS 1
__device__ __forceinline__ void glds16(const unsigned short* g, unsigned short* l) {
  __builtin_amdgcn_global_load_lds(
      (const __attribute__((address_space(1))) void*)g,
      (__attribute__((address_space(3))) void*)l, 16, 0, 0);
}
#else
#define HAS_GLDS 0
#endif

// ---------- LayerNorm: one WAVE per row of D=1024; 4 rows/block ----------
__global__ __launch_bounds__(256) void ln_kernel(
    const float* __restrict__ x, const float* __restrict__ g,
    const float* __restrict__ b, unsigned short* __restrict__ obf,
    float* __restrict__ of32) {
  const int row = blockIdx.x * 4 + (threadIdx.x >> 6);
  const int lane = threadIdx.x & 63;
  const float4* xr = (const float4*)(x + (size_t)row * CD);
  float4 v[4];
#pragma unroll
  for (int k = 0; k < 4; ++k) v[k] = xr[lane + 64 * k];
  float s = 0.f, s2 = 0.f;
#pragma unroll
  for (int k = 0; k < 4; ++k) {
    s  += v[k].x + v[k].y + v[k].z + v[k].w;
    s2 += v[k].x*v[k].x + v[k].y*v[k].y + v[k].z*v[k].z + v[k].w*v[k].w;
  }
#pragma unroll
  for (int off = 32; off; off >>= 1) { s += __shfl_xor(s, off); s2 += __shfl_xor(s2, off); }
  const float mean = s * (1.0f / 1024.0f);
  const float var  = s2 * (1.0f / 1024.0f) - mean * mean;   // == jnp.var (ddof=0)
  const float rstd = rsqrtf(var + 1e-5f);
#pragma unroll
  for (int k = 0; k < 4; ++k) {
    const float4 gv = ((const float4*)g)[lane + 64 * k];
    const float4 bv = ((const float4*)b)[lane + 64 * k];
    float4 y;
    y.x = (v[k].x - mean) * rstd * gv.x + bv.x;
    y.y = (v[k].y - mean) * rstd * gv.y + bv.y;
    y.z = (v[k].z - mean) * rstd * gv.z + bv.z;
    y.w = (v[k].w - mean) * rstd * gv.w + bv.w;
    ushort4 o; o.x = f2bf(y.x); o.y = f2bf(y.y); o.z = f2bf(y.z); o.w = f2bf(y.w);
    ((ushort4*)(obf + (size_t)row * CD))[lane + 64 * k] = o;
    if (of32) ((float4*)(of32 + (size_t)row * CD))[lane + 64 * k] = y;
  }
}

// ---------- weight transpose + bf16 convert: W[K][N] f32 -> WT[N][K] bf16 ----
__global__ __launch_bounds__(256) void wtrans_kernel(
    const float* __restrict__ W, unsigned short* __restrict__ WT, int K, int N) {
  __shared__ float t[64][65];
  const int n0 = blockIdx.x * 64, k0 = blockIdx.y * 64;
  const int tid = threadIdx.x;
  const int kr = tid >> 4, ns = (tid & 15) * 4;
#pragma unroll
  for (int i = 0; i < 4; ++i) {
    const int k = kr + i * 16;
    const float4 v = *(const float4*)&W[(size_t)(k0 + k) * N + n0 + ns];
    t[k][ns + 0] = v.x; t[k][ns + 1] = v.y; t[k][ns + 2] = v.z; t[k][ns + 3] = v.w;
  }
  __syncthreads();
  const int n = tid >> 2, ks = (tid & 3) * 16;
#pragma unroll
  for (int c = 0; c < 4; ++c) {
    ushort4 o;
    o.x = f2bf(t[ks + c * 4 + 0][n]);
    o.y = f2bf(t[ks + c * 4 + 1][n]);
    o.z = f2bf(t[ks + c * 4 + 2][n]);
    o.w = f2bf(t[ks + c * 4 + 3][n]);
    *(ushort4*)&WT[(size_t)(n0 + n) * K + k0 + ks + c * 4] = o;
  }
}

// ---------- m97-structure GEMM: C[M,N] = A[M,K] @ BT[N,K]^T (kept for Q/out) --
template <bool A_KV, bool C_BF16>
__global__ __launch_bounds__(256) void gemm128_kernel(
    const unsigned short* __restrict__ A, const unsigned short* __restrict__ xn,
    const unsigned short* __restrict__ lnb, const unsigned short* __restrict__ BT,
    unsigned short* __restrict__ Cb, float* __restrict__ Cf,
    int M, int N, int K) {
  __shared__ __attribute__((aligned(16))) unsigned short As[128 * 32];
  __shared__ __attribute__((aligned(16))) unsigned short Bs[128 * 32];
  const int tid = threadIdx.x;
  const int col0 = blockIdx.x * 128, row0 = blockIdx.y * 128;
  const int srow = tid >> 2, skseg = (tid & 3) * 8;

  auto arow_ptr = [&](int grow) -> const unsigned short* {
    if (grow >= M) grow = M - 1;
    if (A_KV) {
      const int bt = grow / CNK, j = grow - bt * CNK;
      return (j < CN1) ? xn + ((size_t)(bt * CN1 + j)) * K + skseg
                       : lnb + ((size_t)(bt * CN2)) * K + skseg;  // ln[:, :, 0]
    }
    return A + (size_t)grow * K + skseg;
  };
  const unsigned short* a0 = arow_ptr(row0 + srow);
  const unsigned short* a1 = arow_ptr(row0 + 64 + srow);
  const unsigned short* b0 = BT + (size_t)(col0 + srow) * K + skseg;
  const unsigned short* b1 = BT + (size_t)(col0 + 64 + srow) * K + skseg;

  const int lane = tid & 63, wave = tid >> 6;
  const int wrow = (wave >> 1) * 64, wcol = (wave & 1) * 64;
  const int i16 = lane & 15, quad = lane >> 4;

  floatx4 acc[4][4] = {};
  for (int kt = 0; kt < K; kt += 32) {
    __syncthreads();
#if HAS_GLDS
    glds16(a0 + kt, &As[tid * 8]);
    glds16(a1 + kt, &As[2048 + tid * 8]);
    glds16(b0 + kt, &Bs[tid * 8]);
    glds16(b1 + kt, &Bs[2048 + tid * 8]);
#else
    *(uint4*)&As[tid * 8]        = *(const uint4*)(a0 + kt);
    *(uint4*)&As[2048 + tid * 8] = *(const uint4*)(a1 + kt);
    *(uint4*)&Bs[tid * 8]        = *(const uint4*)(b0 + kt);
    *(uint4*)&Bs[2048 + tid * 8] = *(const uint4*)(b1 + kt);
#endif
    __syncthreads();
    short8 af[4], bf[4];
#pragma unroll
    for (int ti = 0; ti < 4; ++ti)
      af[ti] = *(const short8*)&As[(wrow + ti * 16 + i16) * 32 + quad * 8];
#pragma unroll
    for (int tj = 0; tj < 4; ++tj)
      bf[tj] = *(const short8*)&Bs[(wcol + tj * 16 + i16) * 32 + quad * 8];
#pragma unroll
    for (int ti = 0; ti < 4; ++ti)
#pragma unroll
      for (int tj = 0; tj < 4; ++tj)
        acc[ti][tj] = mfma_bf16(af[ti], bf[tj], acc[ti][tj]);
  }
#pragma unroll
  for (int ti = 0; ti < 4; ++ti)
#pragma unroll
    for (int tj = 0; tj < 4; ++tj) {
      const int gc = col0 + wcol + tj * 16 + i16;
#pragma unroll
      for (int r = 0; r < 4; ++r) {
        const int gr = row0 + wrow + ti * 16 + quad * 4 + r;
        if (gr < M) {
          if (C_BF16) Cb[(size_t)gr * N + gc] = f2bf(acc[ti][tj][r]);
          else        Cf[(size_t)gr * N + gc] = acc[ti][tj][r];
        }
      }
    }
}

// ---------- 256^2-tile deep-pipelined GEMM for the big KV matmul ----------
// 8 waves (2M x 4N), per-wave output 128x64. K in 32-wide slices; 4-slot LDS
// ring per operand (128 KiB total). Per phase: stage slice s+3 (4 glds) ||
// ds_read slice s (B-frags FIRST, A-frags rolling 2 ahead of their MFMA
// group) || 32 MFMA. ONE barrier + counted vmcnt per phase; vmcnt never 0
// until the true tail (8/8/4/0 schedule -> every phase provably sees its
// slice landed, incl. the last 3 where no new stage is issued).
// Read-order rationale: MFMA group ti depends only on reads <= 6+ti, so the
// compiler's counted lgkmcnt rolls (7),(6),... and the ~1150cy LDS read
// stream hides under the ~1240cy MFMA shadow instead of serializing with it.
// Bank swizzle: slot16 = quad ^ ((row>>1)&3) on the read side, inverse
// permutation applied to the GLOBAL source address (linear LDS dest for
// global_load_lds) -- both-sides-or-neither.
template <bool A_KV>
__global__ __launch_bounds__(512, 2) void gemm256_kernel(
    const unsigned short* __restrict__ A, const unsigned short* __restrict__ xn,
    const unsigned short* __restrict__ lnb, const unsigned short* __restrict__ BT,
    unsigned short* __restrict__ Cb,
    int M, int N, int K, int nbN) {
  __shared__ __attribute__((aligned(16))) unsigned short As[4 * 8192];
  __shared__ __attribute__((aligned(16))) unsigned short Bs[4 * 8192];
  const int tid = threadIdx.x;

  // bijective XCD swizzle (grid is a multiple of 8 by construction)
  const int raw = blockIdx.x;
  const int cpx = gridDim.x >> 3;
  const int virt = (raw & 7) * cpx + (raw >> 3);
  const int mb = virt / nbN, nb = virt - mb * nbN;
  const int row0 = mb * 256, col0 = nb * 256;

  auto arow = [&](int grow) -> const unsigned short* {
    if (grow >= M) grow = M - 1;
    if (A_KV) {
      const int bt = grow / CNK, j = grow - bt * CNK;
      return (j < CN1) ? xn + ((size_t)(bt * CN1 + j)) * K
                       : lnb + ((size_t)(bt * CN2)) * K;   // ln[:, :, 0]
    }
    return A + (size_t)grow * K;
  };
  const int c0 = tid, c1 = tid + 512;
  const int rA0 = c0 >> 2, sA0 = (c0 & 3) ^ ((rA0 >> 1) & 3);
  const int rA1 = c1 >> 2, sA1 = (c1 & 3) ^ ((rA1 >> 1) & 3);
  const unsigned short* pA0 = arow(row0 + rA0) + sA0 * 8;
  const unsigned short* pA1 = arow(row0 + rA1) + sA1 * 8;
  const unsigned short* pB0 = BT + (size_t)(col0 + rA0) * K + sA0 * 8;
  const unsigned short* pB1 = BT + (size_t)(col0 + rA1) * K + sA1 * 8;

  auto stage = [&](int s) {
    const int sb = (s & 3) * 8192;
#if HAS_GLDS
    glds16(pA0 + s * 32, &As[sb + tid * 8]);
    glds16(pA1 + s * 32, &As[sb + 4096 + tid * 8]);
    glds16(pB0 + s * 32, &Bs[sb + tid * 8]);
    glds16(pB1 + s * 32, &Bs[sb + 4096 + tid * 8]);
#else
    *(uint4*)&As[sb + tid * 8]        = *(const uint4*)(pA0 + s * 32);
    *(uint4*)&As[sb + 4096 + tid * 8] = *(const uint4*)(pA1 + s * 32);
    *(uint4*)&Bs[sb + tid * 8]        = *(const uint4*)(pB0 + s * 32);
    *(uint4*)&Bs[sb + 4096 + tid * 8] = *(const uint4*)(pB1 + s * 32);
#endif
  };

  // ----- fragment read offsets (swizzled), constant per thread -----
  const int lane = tid & 63, wave = tid >> 6;
  const int wr = wave >> 2, wc = wave & 3;
  const int i16 = lane & 15, quad = lane >> 4;
  int offA[8], offB[4];
#pragma unroll
  for (int ti = 0; ti < 8; ++ti) {
    const int r = wr * 128 + ti * 16 + i16;
    offA[ti] = r * 32 + (quad ^ ((r >> 1) & 3)) * 8;
  }
#pragma unroll
  for (int tj = 0; tj < 4; ++tj) {
    const int r = wc * 64 + tj * 16 + i16;
    offB[tj] = r * 32 + (quad ^ ((r >> 1) & 3)) * 8;
  }

  floatx4 acc[8][4] = {};
  const int NSL = K >> 5;           // slices of K=32
  stage(0); stage(1); stage(2);     // 3-deep prologue (12 loads/thread)

  // phase body: stage first, B-frags, then A-frags rolling 2 ahead of use.
  auto phase = [&](int s, bool do_stage) {
    const unsigned short* Asl = &As[(s & 3) * 8192];
    const unsigned short* Bsl = &Bs[(s & 3) * 8192];
    if (do_stage) stage(s + 3);
    short8 bf[4];
#pragma unroll
    for (int tj = 0; tj < 4; ++tj) bf[tj] = *(const short8*)(Bsl + offB[tj]);
    short8 af[8];
    af[0] = *(const short8*)(Asl + offA[0]);
    af[1] = *(const short8*)(Asl + offA[1]);
    __builtin_amdgcn_s_setprio(1);
#pragma unroll
    for (int ti = 0; ti < 8; ++ti) {
      if (ti + 2 < 8) af[ti + 2] = *(const short8*)(Asl + offA[ti + 2]);
#pragma unroll
      for (int tj = 0; tj < 4; ++tj)
        acc[ti][tj] = mfma_bf16(af[ti], bf[tj], acc[ti][tj]);
    }
    __builtin_amdgcn_s_setprio(0);
  };

  for (int s = 0; s < NSL - 3; ++s) {   // stage(s+3) always valid here
    asm volatile("s_waitcnt vmcnt(8)" ::: "memory");
    __builtin_amdgcn_s_barrier();
    __builtin_amdgcn_sched_barrier(0);
    phase(s, true);
  }
  // tail: no new stages; counted waits shrink 8 -> 4 -> 0 so each phase
  // still provably sees its slice landed.
  asm volatile("s_waitcnt vmcnt(8)" ::: "memory");
  __builtin_amdgcn_s_barrier();
  __builtin_amdgcn_sched_barrier(0);
  phase(NSL - 3, false);
  asm volatile("s_waitcnt vmcnt(4)" ::: "memory");
  __builtin_amdgcn_s_barrier();
  __builtin_amdgcn_sched_barrier(0);
  phase(NSL - 2, false);
  asm volatile("s_waitcnt vmcnt(0)" ::: "memory");
  __builtin_amdgcn_s_barrier();
  __builtin_amdgcn_sched_barrier(0);
  phase(NSL - 1, false);

#pragma unroll
  for (int ti = 0; ti < 8; ++ti)
#pragma unroll
    for (int tj = 0; tj < 4; ++tj) {
      const int gc = col0 + wc * 64 + tj * 16 + i16;
#pragma unroll
      for (int r = 0; r < 4; ++r) {
        const int gr = row0 + wr * 128 + ti * 16 + quad * 4 + r;
        if (gr < M) Cb[(size_t)gr * N + gc] = f2bf(acc[ti][tj][r]);
      }
    }
}

// ---------- dynamic per-head weights: one block per (b,t) ----------
__global__ __launch_bounds__(256) void dw_kernel(
    const float* __restrict__ lnf, const float* __restrict__ Wd1,
    const float* __restrict__ bd1, const float* __restrict__ Wd2,
    const float* __restrict__ bd2, float* __restrict__ dw) {
  __shared__ float mean[CD];
  __shared__ float hid[256];
  __shared__ float lg[16];
  const int bt = blockIdx.x, tid = threadIdx.x;
  const float* base = lnf + (size_t)bt * CN2 * CD;
  for (int d = tid; d < CD; d += 256) {
    float s = 0.f;
    for (int r = 0; r < CN2; ++r) s += base[(size_t)r * CD + d];
    mean[d] = s * (1.0f / 64.0f);
  }
  __syncthreads();
  {
    float s = bd1[tid];
    for (int d = 0; d < CD; ++d) s += mean[d] * Wd1[(size_t)d * 256 + tid];
    hid[tid] = fmaxf(s, 0.0f);
  }
  __syncthreads();
  if (tid < 16) {
    float s = bd2[tid];
    for (int o = 0; o < 256; ++o) s += hid[o] * Wd2[o * 16 + tid];
    lg[tid] = s;
  }
  __syncthreads();
  if (tid < 16) {
    float mx = lg[0];
    for (int h = 1; h < 16; ++h) mx = fmaxf(mx, lg[h]);
    float sum = 0.f;
    for (int h = 0; h < 16; ++h) sum += __expf(lg[h] - mx);
    dw[bt * 16 + tid] = __expf(lg[tid] - mx) / sum;
  }
}

// ---------- MFMA attention v2: block per (b,t,h), 4 waves x 16 q-rows ----------
__global__ __launch_bounds__(256) void attn_kernel(
    const unsigned short* __restrict__ Q,   // (BT*64) x 1024, col = h*64+d
    const unsigned short* __restrict__ KV,  // (BT*1025) x 2048, K then V
    const float* __restrict__ dw,           // BT x 16
    unsigned short* __restrict__ AO) {      // (BT*64) x 1024, col = h*64+d
  __shared__ __attribute__((aligned(16))) unsigned short ks[2][64 * 72];  // K: [key][d]
  __shared__ __attribute__((aligned(16))) unsigned short vt[2][64 * 72];  // V^T: [d][perm key]
  const int bt = blockIdx.x >> 4, h = blockIdx.x & 15;
  const int tid = threadIdx.x;
  const int lane = tid & 63, wave = tid >> 6;
  const int i16 = lane & 15, quad = lane >> 4;
  const int wrow = wave * 16;

  const unsigned short* qbase =
      Q + ((size_t)(bt * 64 + wrow + i16)) * CINNER + h * 64;
  const short8 bq0 = *(const short8*)(qbase + quad * 8);        // d 0..31
  const short8 bq1 = *(const short8*)(qbase + 32 + quad * 8);   // d 32..63

  const int jrb = tid & 31, seg = tid >> 5;
  const int t_ = jrb & 15, hlf_ = jrb >> 4;
  const int vcol0 = ((t_ >> 2) << 3) + (t_ & 3) + 4 * hlf_;  // + c*32
  const unsigned short* kvb = KV + ((size_t)bt * CNK) * 2048 + h * 64 + seg * 8;

  uint4 kk[2], vv[2];
  auto load_tile = [&](int j0) {
#pragma unroll
    for (int c = 0; c < 2; ++c) {
      const int j = j0 + c * 32 + jrb;
      if (j < CNK) {
        const unsigned short* p = kvb + (size_t)j * 2048;
        kk[c] = *(const uint4*)p;
        vv[c] = *(const uint4*)(p + 1024);
      } else {
        kk[c] = make_uint4(0, 0, 0, 0);
        vv[c] = make_uint4(0, 0, 0, 0);
      }
    }
  };
  auto write_tile = [&](int buf) {
#pragma unroll
    for (int c = 0; c < 2; ++c) {
      const int jr = c * 32 + jrb;
      *(uint4*)&ks[buf][jr * 72 + seg * 8] = kk[c];
      const int vcol = c * 32 + vcol0;
      const unsigned int w[4] = {vv[c].x, vv[c].y, vv[c].z, vv[c].w};
#pragma unroll
      for (int p = 0; p < 4; ++p) {
        vt[buf][(seg * 8 + 2 * p + 0) * 72 + vcol] = (unsigned short)(w[p] & 0xffffu);
        vt[buf][(seg * 8 + 2 * p + 1) * 72 + vcol] = (unsigned short)(w[p] >> 16);
      }
    }
  };

  float l = 0.f;
  floatx4 O[4] = {{0,0,0,0}, {0,0,0,0}, {0,0,0,0}, {0,0,0,0}};
  const float expC = 0.18033688011112042f;  // 0.125 * log2(e)

  load_tile(0);
  write_tile(0);
  constexpr int NT = 17;  // ceil(1025/64)
  for (int t = 0; t < NT; ++t) {
    if (t + 1 < NT) load_tile((t + 1) * 64);
    __syncthreads();
    const int buf = t & 1;
    const unsigned short* ksb = ks[buf];
    const unsigned short* vtb = vt[buf];
#pragma unroll
    for (int c = 0; c < 2; ++c) {
      floatx4 s0 = {0,0,0,0}, s1 = {0,0,0,0};
      const short8 a00 = *(const short8*)&ksb[((2*c)   * 16 + i16) * 72 + quad * 8];
      const short8 a01 = *(const short8*)&ksb[((2*c)   * 16 + i16) * 72 + 32 + quad * 8];
      const short8 a10 = *(const short8*)&ksb[((2*c+1) * 16 + i16) * 72 + quad * 8];
      const short8 a11 = *(const short8*)&ksb[((2*c+1) * 16 + i16) * 72 + 32 + quad * 8];
      s0 = mfma_bf16(a00, bq0, s0); s0 = mfma_bf16(a01, bq1, s0);
      s1 = mfma_bf16(a10, bq0, s1); s1 = mfma_bf16(a11, bq1, s1);
      unsigned short pb0[4], pb1[4];
      if (t == NT - 1) {  // masked tail tile (keys 1024..1087; only 1024 valid)
#pragma unroll
        for (int r = 0; r < 4; ++r) {
          const int k0g = t * 64 + (2*c)   * 16 + quad * 4 + r;
          const int k1g = t * 64 + (2*c+1) * 16 + quad * 4 + r;
          const float p0 = (k0g < CNK) ? exp2f(s0[r] * expC) : 0.f;
          const float p1 = (k1g < CNK) ? exp2f(s1[r] * expC) : 0.f;
          l += p0 + p1;
          pb0[r] = f2bf(p0); pb1[r] = f2bf(p1);
        }
      } else {
#pragma unroll
        for (int r = 0; r < 4; ++r) {
          const float p0 = exp2f(s0[r] * expC);
          const float p1 = exp2f(s1[r] * expC);
          l += p0 + p1;
          pb0[r] = f2bf(p0); pb1[r] = f2bf(p1);
        }
      }
      const short8 bp = {
          (short)pb0[0], (short)pb0[1], (short)pb0[2], (short)pb0[3],
          (short)pb1[0], (short)pb1[1], (short)pb1[2], (short)pb1[3]};
#pragma unroll
      for (int dt = 0; dt < 4; ++dt) {
        const short8 av = *(const short8*)&vtb[(dt * 16 + i16) * 72 + c * 32 + quad * 8];
        O[dt] = mfma_bf16(av, bp, O[dt]);
      }
    }
    if (t + 1 < NT) write_tile((t + 1) & 1);
  }

  l += __shfl_xor(l, 16);
  l += __shfl_xor(l, 32);
  const float wsc = dw[bt * 16 + h] / l;
  unsigned short* obase = AO + ((size_t)(bt * 64 + wrow + i16)) * CINNER + h * 64;
#pragma unroll
  for (int dt = 0; dt < 4; ++dt)
#pragma unroll
    for (int r = 0; r < 4; ++r)
      obase[dt * 16 + quad * 4 + r] = f2bf(O[dt][r] * wsc);
}

// ---------- host ----------
extern "C" void kernel_launch(void* const* d_in, const int* in_sizes, int n_in,
                              void* d_out, int out_size, void* d_ws, size_t ws_size,
                              hipStream_t stream) {
  const float* x       = (const float*)d_in[0];
  const float* latents = (const float*)d_in[1];
  const float* gm  = (const float*)d_in[2];
  const float* bm  = (const float*)d_in[3];
  const float* gl  = (const float*)d_in[4];
  const float* bl  = (const float*)d_in[5];
  const float* Wq  = (const float*)d_in[6];
  const float* Wkv = (const float*)d_in[7];
  const float* Wout= (const float*)d_in[8];
  const float* Wd1 = (const float*)d_in[9];
  const float* bd1 = (const float*)d_in[10];
  const float* Wd2 = (const float*)d_in[11];
  const float* bd2 = (const float*)d_in[12];
  float* out = (float*)d_out;

  char* ws = (char*)d_ws;
  size_t off = 0;
  auto alloc = [&](size_t bytes) -> void* {
    void* p = ws + off;
    off += (bytes + 255) & ~(size_t)255;
    return p;
  };
  unsigned short* xn   = (unsigned short*)alloc((size_t)CBT * CN1 * CD * 2);      // 64 MB
  unsigned short* kv   = (unsigned short*)alloc((size_t)CBT * CNK * 2048 * 2);    // 131 MB
  float*          lnf  = (float*)        alloc((size_t)CBT * CN2 * CD * 4);       // 8 MB
  unsigned short* lnb  = (unsigned short*)alloc((size_t)CBT * CN2 * CD * 2);      // 4 MB
  unsigned short* wqT  = (unsigned short*)alloc((size_t)CD * CINNER * 2);         // 2 MB  [N][K]
  unsigned short* wkvT = (unsigned short*)alloc((size_t)CD * 2 * CINNER * 2);     // 4 MB  [2N][K]
  unsigned short* woT  = (unsigned short*)alloc((size_t)CINNER * CD * 2);         // 2 MB  [N][K]
  unsigned short* qb   = (unsigned short*)alloc((size_t)CBT * CN2 * CINNER * 2);  // 4 MB
  unsigned short* aob  = (unsigned short*)alloc((size_t)CBT * CN2 * CINNER * 2);  // 4 MB
  float*          dwp  = (float*)        alloc((size_t)CBT * CH * 4);
  if (off > ws_size) return;  // signal: output stays zero (ws too small)

  // 1) layernorms (x -> bf16; latents -> bf16 + fp32)
  ln_kernel<<<CBT * CN1 / 4, 256, 0, stream>>>(x, gm, bm, xn, nullptr);
  ln_kernel<<<CBT * CN2 / 4, 256, 0, stream>>>(latents, gl, bl, lnb, lnf);
  // 2) weight transpose + bf16 convert: W[K][N] -> WT[N][K]
  wtrans_kernel<<<dim3(CINNER / 64, CD / 64), 256, 0, stream>>>(Wq, wqT, CD, CINNER);
  wtrans_kernel<<<dim3(2 * CINNER / 64, CD / 64), 256, 0, stream>>>(Wkv, wkvT, CD, 2 * CINNER);
  wtrans_kernel<<<dim3(CD / 64, CINNER / 64), 256, 0, stream>>>(Wout, woT, CINNER, CD);
  // 3) Q = ln @ Wq   (2048 x 1024 x 1024) -- small M: keep 128^2 kernel
  gemm128_kernel<false, true><<<dim3(1024 / 128, 2048 / 128), 256, 0, stream>>>(
      lnb, nullptr, nullptr, wqT, qb, nullptr, 2048, 1024, 1024);
  // 4) KV = concat(xn, ln[:, :, 0:1]) @ Wkv   (32800 x 2048 x 1024)
  //    256^2-tile deep-pipelined kernel; grid = ceil(M/256) * (N/256) = 129*8
  {
    const int MB = (CBT * CNK + 255) / 256;   // 129
    gemm256_kernel<true><<<MB * 8, 512, 0, stream>>>(
        nullptr, xn, lnb, wkvT, kv, CBT * CNK, 2048, 1024, 8);
  }
  // 5) dynamic head weights
  dw_kernel<<<CBT, 256, 0, stream>>>(lnf, Wd1, bd1, Wd2, bd2, dwp);
  // 6) attention (512 blocks = BT * H)
  attn_kernel<<<CBT * CH, 256, 0, stream>>>(qb, kv, dwp, aob);
  // 7) out = AO @ Wout   (2048 x 1024 x 1024) -> fp32 d_out
  gemm128_kernel<false, false><<<dim3(1024 / 128, 2048 / 128), 256, 0, stream>>>(
      aob, nullptr, nullptr, woT, nullptr, out, 2048, 1024, 1024);
}

// Round 3
// 529.794 us; speedup vs baseline: 1.1137x; 1.1137x over previous
//
#include <hip/hip_runtime.h>
#include <cstdint>
#include <cstddef>

// Problem constants (B=8,T=4,N1=1024,N2=64,D=1024,H=16,DH=64)
constexpr int CB = 8, CT = 4, CN1 = 1024, CN2 = 64, CD = 1024, CH = 16, CDH = 64;
constexpr int CBT = CB * CT;          // 32
constexpr int CNK = CN1 + 1;          // 1025
constexpr int CINNER = CH * CDH;      // 1024

// ---------- bf16 helpers (raw ushort storage) ----------
__device__ __forceinline__ unsigned short f2bf(float f) {
  union { float f; unsigned int u; } v; v.f = f;
  unsigned int u = v.u;
  u += 0x7fffu + ((u >> 16) & 1u);    // RNE
  return (unsigned short)(u >> 16);
}

// ---------- MFMA types ----------
typedef __attribute__((ext_vector_type(8))) short short8;
typedef __attribute__((ext_vector_type(8))) __bf16 bf16x8;
typedef __attribute__((ext_vector_type(4))) float floatx4;

template <typename V>
__device__ __forceinline__ auto mfma_bf16_impl(V a, V b, floatx4 c, int)
    -> decltype(__builtin_amdgcn_mfma_f32_16x16x32_bf16(a, b, c, 0, 0, 0)) {
  return __builtin_amdgcn_mfma_f32_16x16x32_bf16(a, b, c, 0, 0, 0);
}
template <typename V>
__device__ __forceinline__ floatx4 mfma_bf16_impl(V a, V b, floatx4 c, long) {
  return __builtin_amdgcn_mfma_f32_16x16x32_bf16(
      __builtin_bit_cast(bf16x8, a), __builtin_bit_cast(bf16x8, b), c, 0, 0, 0);
}
__device__ __forceinline__ floatx4 mfma_bf16(short8 a, short8 b, floatx4 c) {
  return mfma_bf16_impl(a, b, c, 0);
}

// ---------- async global->LDS (16B/lane), guarded w/ manual fallback ----------
#if __has_builtin(__builtin_amdgcn_global_load_lds)
#define HAS_GLDS 1
__device__ __forceinline__ void glds16(const unsigned short* g, unsigned short* l) {
  __builtin_amdgcn_global_load_lds(
      (const __attribute__((address_space(1))) void*)g,
      (__attribute__((address_space(3))) void*)l, 16, 0, 0);
}
#else
#define HAS_GLDS 0
#endif

// ---------- LayerNorm: one WAVE per row of D=1024; 4 rows/block ----------
__global__ __launch_bounds__(256) void ln_kernel(
    const float* __restrict__ x, const float* __restrict__ g,
    const float* __restrict__ b, unsigned short* __restrict__ obf,
    float* __restrict__ of32) {
  const int row = blockIdx.x * 4 + (threadIdx.x >> 6);
  const int lane = threadIdx.x & 63;
  const float4* xr = (const float4*)(x + (size_t)row * CD);
  float4 v[4];
#pragma unroll
  for (int k = 0; k < 4; ++k) v[k] = xr[lane + 64 * k];
  float s = 0.f, s2 = 0.f;
#pragma unroll
  for (int k = 0; k < 4; ++k) {
    s  += v[k].x + v[k].y + v[k].z + v[k].w;
    s2 += v[k].x*v[k].x + v[k].y*v[k].y + v[k].z*v[k].z + v[k].w*v[k].w;
  }
#pragma unroll
  for (int off = 32; off; off >>= 1) { s += __shfl_xor(s, off); s2 += __shfl_xor(s2, off); }
  const float mean = s * (1.0f / 1024.0f);
  const float var  = s2 * (1.0f / 1024.0f) - mean * mean;   // == jnp.var (ddof=0)
  const float rstd = rsqrtf(var + 1e-5f);
#pragma unroll
  for (int k = 0; k < 4; ++k) {
    const float4 gv = ((const float4*)g)[lane + 64 * k];
    const float4 bv = ((const float4*)b)[lane + 64 * k];
    float4 y;
    y.x = (v[k].x - mean) * rstd * gv.x + bv.x;
    y.y = (v[k].y - mean) * rstd * gv.y + bv.y;
    y.z = (v[k].z - mean) * rstd * gv.z + bv.z;
    y.w = (v[k].w - mean) * rstd * gv.w + bv.w;
    ushort4 o; o.x = f2bf(y.x); o.y = f2bf(y.y); o.z = f2bf(y.z); o.w = f2bf(y.w);
    ((ushort4*)(obf + (size_t)row * CD))[lane + 64 * k] = o;
    if (of32) ((float4*)(of32 + (size_t)row * CD))[lane + 64 * k] = y;
  }
}

// ---------- weight transpose + bf16 convert: W[K][N] f32 -> WT[N][K] bf16 ----
__global__ __launch_bounds__(256) void wtrans_kernel(
    const float* __restrict__ W, unsigned short* __restrict__ WT, int K, int N) {
  __shared__ float t[64][65];
  const int n0 = blockIdx.x * 64, k0 = blockIdx.y * 64;
  const int tid = threadIdx.x;
  const int kr = tid >> 4, ns = (tid & 15) * 4;
#pragma unroll
  for (int i = 0; i < 4; ++i) {
    const int k = kr + i * 16;
    const float4 v = *(const float4*)&W[(size_t)(k0 + k) * N + n0 + ns];
    t[k][ns + 0] = v.x; t[k][ns + 1] = v.y; t[k][ns + 2] = v.z; t[k][ns + 3] = v.w;
  }
  __syncthreads();
  const int n = tid >> 2, ks = (tid & 3) * 16;
#pragma unroll
  for (int c = 0; c < 4; ++c) {
    ushort4 o;
    o.x = f2bf(t[ks + c * 4 + 0][n]);
    o.y = f2bf(t[ks + c * 4 + 1][n]);
    o.z = f2bf(t[ks + c * 4 + 2][n]);
    o.w = f2bf(t[ks + c * 4 + 3][n]);
    *(ushort4*)&WT[(size_t)(n0 + n) * K + k0 + ks + c * 4] = o;
  }
}

// ---------- m97-structure GEMM: C[M,N] = A[M,K] @ BT[N,K]^T (Q/out GEMMs) ----
template <bool A_KV, bool C_BF16>
__global__ __launch_bounds__(256) void gemm128_kernel(
    const unsigned short* __restrict__ A, const unsigned short* __restrict__ xn,
    const unsigned short* __restrict__ lnb, const unsigned short* __restrict__ BT,
    unsigned short* __restrict__ Cb, float* __restrict__ Cf,
    int M, int N, int K) {
  __shared__ __attribute__((aligned(16))) unsigned short As[128 * 32];
  __shared__ __attribute__((aligned(16))) unsigned short Bs[128 * 32];
  const int tid = threadIdx.x;
  const int col0 = blockIdx.x * 128, row0 = blockIdx.y * 128;
  const int srow = tid >> 2, skseg = (tid & 3) * 8;

  auto arow_ptr = [&](int grow) -> const unsigned short* {
    if (grow >= M) grow = M - 1;
    if (A_KV) {
      const int bt = grow / CNK, j = grow - bt * CNK;
      return (j < CN1) ? xn + ((size_t)(bt * CN1 + j)) * K + skseg
                       : lnb + ((size_t)(bt * CN2)) * K + skseg;  // ln[:, :, 0]
    }
    return A + (size_t)grow * K + skseg;
  };
  const unsigned short* a0 = arow_ptr(row0 + srow);
  const unsigned short* a1 = arow_ptr(row0 + 64 + srow);
  const unsigned short* b0 = BT + (size_t)(col0 + srow) * K + skseg;
  const unsigned short* b1 = BT + (size_t)(col0 + 64 + srow) * K + skseg;

  const int lane = tid & 63, wave = tid >> 6;
  const int wrow = (wave >> 1) * 64, wcol = (wave & 1) * 64;
  const int i16 = lane & 15, quad = lane >> 4;

  floatx4 acc[4][4] = {};
  for (int kt = 0; kt < K; kt += 32) {
    __syncthreads();
#if HAS_GLDS
    glds16(a0 + kt, &As[tid * 8]);
    glds16(a1 + kt, &As[2048 + tid * 8]);
    glds16(b0 + kt, &Bs[tid * 8]);
    glds16(b1 + kt, &Bs[2048 + tid * 8]);
#else
    *(uint4*)&As[tid * 8]        = *(const uint4*)(a0 + kt);
    *(uint4*)&As[2048 + tid * 8] = *(const uint4*)(a1 + kt);
    *(uint4*)&Bs[tid * 8]        = *(const uint4*)(b0 + kt);
    *(uint4*)&Bs[2048 + tid * 8] = *(const uint4*)(b1 + kt);
#endif
    __syncthreads();
    short8 af[4], bf[4];
#pragma unroll
    for (int ti = 0; ti < 4; ++ti)
      af[ti] = *(const short8*)&As[(wrow + ti * 16 + i16) * 32 + quad * 8];
#pragma unroll
    for (int tj = 0; tj < 4; ++tj)
      bf[tj] = *(const short8*)&Bs[(wcol + tj * 16 + i16) * 32 + quad * 8];
#pragma unroll
    for (int ti = 0; ti < 4; ++ti)
#pragma unroll
      for (int tj = 0; tj < 4; ++tj)
        acc[ti][tj] = mfma_bf16(af[ti], bf[tj], acc[ti][tj]);
  }
#pragma unroll
  for (int ti = 0; ti < 4; ++ti)
#pragma unroll
    for (int tj = 0; tj < 4; ++tj) {
      const int gc = col0 + wcol + tj * 16 + i16;
#pragma unroll
      for (int r = 0; r < 4; ++r) {
        const int gr = row0 + wrow + ti * 16 + quad * 4 + r;
        if (gr < M) {
          if (C_BF16) Cb[(size_t)gr * N + gc] = f2bf(acc[ti][tj][r]);
          else        Cf[(size_t)gr * N + gc] = acc[ti][tj][r];
        }
      }
    }
}

// ---------- KV GEMM: 128^2 tile, 4 waves, 3-slot ring, counted vmcnt -------
// Design: 3 blocks/CU (48 KiB LDS each) gives three INDEPENDENT barrier
// groups per CU -- cross-block overlap covers per-phase read->MFMA
// serialization (m97's mechanism) while the 3-slot ring keeps vmcnt counted
// (never 0 in the main loop; m201's mechanism).
// Per phase (slice s of K=32): vmcnt(4) BEFORE barrier (each wave's slice-s
// loads landed before it arrives => barrier release implies all waves'
// loads landed); reads 4 B-frags + 4 A-frags; stage slice s+2 (4 glds);
// 16 MFMA. Slot (s+2)%3 == slot (s-1)%3: its readers (phase s-1) completed
// their ds_reads before the phase-s barrier (every read is lgkm-waited
// before its consuming MFMA, which precedes the barrier in program order).
// Tail: phase NSL-2 vmcnt(4) (stage(NSL-2),stage(NSL-1) outstanding);
// phase NSL-1 vmcnt(0).
// Bank swizzle: read k-slot16 = quad ^ ((row>>1)&3); inverse permutation
// applied to the GLOBAL source address (LDS dest stays lane-linear for
// global_load_lds) -- both-sides-or-neither.
template <bool A_KV>
__global__ __launch_bounds__(256) void gemmkv_kernel(
    const unsigned short* __restrict__ xn, const unsigned short* __restrict__ lnb,
    const unsigned short* __restrict__ BT, unsigned short* __restrict__ Cb,
    int M, int N, int K, int nbN) {
  __shared__ __attribute__((aligned(16))) unsigned short As[3 * 4096];
  __shared__ __attribute__((aligned(16))) unsigned short Bs[3 * 4096];
  const int tid = threadIdx.x;

  // bijective XCD swizzle (grid % 8 == 0 by construction)
  const int raw = blockIdx.x;
  const int cpx = gridDim.x >> 3;
  const int virt = (raw & 7) * cpx + (raw >> 3);
  const int mb = virt / nbN, nb = virt - mb * nbN;
  const int row0 = mb * 128, col0 = nb * 128;

  auto arow = [&](int grow) -> const unsigned short* {
    if (grow >= M) grow = M - 1;
    if (A_KV) {
      const int bt = grow / CNK, j = grow - bt * CNK;
      return (j < CN1) ? xn + ((size_t)(bt * CN1 + j)) * K
                       : lnb + ((size_t)(bt * CN2)) * K;   // ln[:, :, 0]
    }
    return (const unsigned short*)nullptr;  // unused
  };
  // staging chunks: slice = 128 rows x 32 shorts (8 KB per operand);
  // 512 chunks of 16B; thread t handles chunks t and t+256 of each operand.
  const int c0 = tid, c1 = tid + 256;
  const int rA0 = c0 >> 2, sA0 = (c0 & 3) ^ ((rA0 >> 1) & 3);
  const int rA1 = c1 >> 2, sA1 = (c1 & 3) ^ ((rA1 >> 1) & 3);
  const unsigned short* pA0 = arow(row0 + rA0) + sA0 * 8;
  const unsigned short* pA1 = arow(row0 + rA1) + sA1 * 8;
  const unsigned short* pB0 = BT + (size_t)(col0 + rA0) * K + sA0 * 8;
  const unsigned short* pB1 = BT + (size_t)(col0 + rA1) * K + sA1 * 8;

  auto stage = [&](int s) {
    const int sb = (s % 3) * 4096;
#if HAS_GLDS
    glds16(pA0 + s * 32, &As[sb + tid * 8]);
    glds16(pA1 + s * 32, &As[sb + 2048 + tid * 8]);
    glds16(pB0 + s * 32, &Bs[sb + tid * 8]);
    glds16(pB1 + s * 32, &Bs[sb + 2048 + tid * 8]);
#else
    *(uint4*)&As[sb + tid * 8]        = *(const uint4*)(pA0 + s * 32);
    *(uint4*)&As[sb + 2048 + tid * 8] = *(const uint4*)(pA1 + s * 32);
    *(uint4*)&Bs[sb + tid * 8]        = *(const uint4*)(pB0 + s * 32);
    *(uint4*)&Bs[sb + 2048 + tid * 8] = *(const uint4*)(pB1 + s * 32);
#endif
  };

  // fragment read offsets (swizzled), constant per thread
  const int lane = tid & 63, wave = tid >> 6;
  const int wr = wave >> 1, wc = wave & 1;     // 2M x 2N, 64x64 per wave
  const int i16 = lane & 15, quad = lane >> 4;
  int offA[4], offB[4];
#pragma unroll
  for (int ti = 0; ti < 4; ++ti) {
    const int r = wr * 64 + ti * 16 + i16;
    offA[ti] = r * 32 + (quad ^ ((r >> 1) & 3)) * 8;
  }
#pragma unroll
  for (int tj = 0; tj < 4; ++tj) {
    const int r = wc * 64 + tj * 16 + i16;
    offB[tj] = r * 32 + (quad ^ ((r >> 1) & 3)) * 8;
  }

  floatx4 acc[4][4] = {};
  const int NSL = K >> 5;           // slices of K=32 (NSL=32 here)
  stage(0); stage(1);               // lag-2 prologue (8 loads/thread)

  auto phase = [&](int s, bool do_stage) {
    const unsigned short* Asl = &As[(s % 3) * 4096];
    const unsigned short* Bsl = &Bs[(s % 3) * 4096];
    short8 bf[4], af[4];
#pragma unroll
    for (int tj = 0; tj < 4; ++tj) bf[tj] = *(const short8*)(Bsl + offB[tj]);
#pragma unroll
    for (int ti = 0; ti < 4; ++ti) af[ti] = *(const short8*)(Asl + offA[ti]);
    if (do_stage) stage(s + 2);
    __builtin_amdgcn_s_setprio(1);
#pragma unroll
    for (int ti = 0; ti < 4; ++ti)
#pragma unroll
      for (int tj = 0; tj < 4; ++tj)
        acc[ti][tj] = mfma_bf16(af[ti], bf[tj], acc[ti][tj]);
    __builtin_amdgcn_s_setprio(0);
  };

  for (int s = 0; s < NSL - 2; ++s) {
    asm volatile("s_waitcnt vmcnt(4)" ::: "memory");
    __builtin_amdgcn_s_barrier();
    __builtin_amdgcn_sched_barrier(0);
    phase(s, true);
  }
  asm volatile("s_waitcnt vmcnt(4)" ::: "memory");
  __builtin_amdgcn_s_barrier();
  __builtin_amdgcn_sched_barrier(0);
  phase(NSL - 2, false);
  asm volatile("s_waitcnt vmcnt(0)" ::: "memory");
  __builtin_amdgcn_s_barrier();
  __builtin_amdgcn_sched_barrier(0);
  phase(NSL - 1, false);

#pragma unroll
  for (int ti = 0; ti < 4; ++ti)
#pragma unroll
    for (int tj = 0; tj < 4; ++tj) {
      const int gc = col0 + wc * 64 + tj * 16 + i16;
#pragma unroll
      for (int r = 0; r < 4; ++r) {
        const int gr = row0 + wr * 64 + ti * 16 + quad * 4 + r;
        if (gr < M) Cb[(size_t)gr * N + gc] = f2bf(acc[ti][tj][r]);
      }
    }
}

// ---------- dynamic head weights, stage 1: mean over latent rows ----------
// grid 128 = (bt, dseg of 256); coalesced 1 KB rows.
__global__ __launch_bounds__(256) void dwmean_kernel(
    const float* __restrict__ lnf, float* __restrict__ meanp) {
  const int bt = blockIdx.x >> 2, dseg = blockIdx.x & 3;
  const int d = dseg * 256 + threadIdx.x;
  const float* base = lnf + (size_t)bt * CN2 * CD + d;
  float s = 0.f;
#pragma unroll 4
  for (int r = 0; r < CN2; ++r) s += base[(size_t)r * CD];
  meanp[bt * CD + d] = s * (1.0f / 64.0f);
}

// ---------- dw stage 2: hid = relu(mean @ Wd1 + bd1) ----------
// grid 256 = (bt, og of 8x32 outputs); thread = (o, dseg of 8).
__global__ __launch_bounds__(256) void dwmlp_kernel(
    const float* __restrict__ meanp, const float* __restrict__ Wd1,
    const float* __restrict__ bd1, float* __restrict__ hidp) {
  __shared__ float red[8][32];
  const int bt = blockIdx.x >> 3, og = blockIdx.x & 7;
  const int o = threadIdx.x & 31, seg = threadIdx.x >> 5;
  const int col = og * 32 + o;
  const float* mb = meanp + bt * CD;
  float s = 0.f;
#pragma unroll 4
  for (int d = seg * 128; d < seg * 128 + 128; ++d)
    s += mb[d] * Wd1[(size_t)d * 256 + col];
  red[seg][o] = s;
  __syncthreads();
  if (seg == 0) {
    float t = red[0][o];
#pragma unroll
    for (int k = 1; k < 8; ++k) t += red[k][o];
    hidp[bt * 256 + col] = fmaxf(t + bd1[col], 0.0f);
  }
}

// ---------- dw stage 3: dw = softmax(hid @ Wd2 + bd2) ----------
// grid 32 = bt; thread = (h, oseg of 16).
__global__ __launch_bounds__(256) void dwfin_kernel(
    const float* __restrict__ hidp, const float* __restrict__ Wd2,
    const float* __restrict__ bd2, float* __restrict__ dw) {
  __shared__ float red[16][16];
  __shared__ float lg[16];
  const int bt = blockIdx.x;
  const int h = threadIdx.x & 15, seg = threadIdx.x >> 4;
  const float* hb = hidp + bt * 256;
  float s = 0.f;
#pragma unroll
  for (int o = seg * 16; o < seg * 16 + 16; ++o)
    s += hb[o] * Wd2[o * 16 + h];
  red[seg][h] = s;
  __syncthreads();
  if (seg == 0) {
    float t = red[0][h];
#pragma unroll
    for (int k = 1; k < 16; ++k) t += red[k][h];
    lg[h] = t + bd2[h];
  }
  __syncthreads();
  if (threadIdx.x < 16) {
    float mx = lg[0];
#pragma unroll
    for (int k = 1; k < 16; ++k) mx = fmaxf(mx, lg[k]);
    float sum = 0.f;
#pragma unroll
    for (int k = 0; k < 16; ++k) sum += __expf(lg[k] - mx);
    dw[bt * 16 + threadIdx.x] = __expf(lg[threadIdx.x] - mx) / sum;
  }
}

// ---------- MFMA attention v2: block per (b,t,h), 4 waves x 16 q-rows ----------
// blockIdx remap groups all 16 heads of one bt onto one XCD (KV tile ~4.2MB
// ~ one XCD's L2) -> KV fetched from HBM once per bt instead of per head.
__global__ __launch_bounds__(256) void attn_kernel(
    const unsigned short* __restrict__ Q,   // (BT*64) x 1024, col = h*64+d
    const unsigned short* __restrict__ KV,  // (BT*1025) x 2048, K then V
    const float* __restrict__ dw,           // BT x 16
    unsigned short* __restrict__ AO) {      // (BT*64) x 1024, col = h*64+d
  __shared__ __attribute__((aligned(16))) unsigned short ks[2][64 * 72];  // K: [key][d]
  __shared__ __attribute__((aligned(16))) unsigned short vt[2][64 * 72];  // V^T: [d][perm key]
  const int raw = blockIdx.x;
  const int bt = (raw & 7) * 4 + ((raw >> 3) >> 4);
  const int h  = (raw >> 3) & 15;
  const int tid = threadIdx.x;
  const int lane = tid & 63, wave = tid >> 6;
  const int i16 = lane & 15, quad = lane >> 4;
  const int wrow = wave * 16;

  const unsigned short* qbase =
      Q + ((size_t)(bt * 64 + wrow + i16)) * CINNER + h * 64;
  const short8 bq0 = *(const short8*)(qbase + quad * 8);        // d 0..31
  const short8 bq1 = *(const short8*)(qbase + 32 + quad * 8);   // d 32..63

  const int jrb = tid & 31, seg = tid >> 5;
  const int t_ = jrb & 15, hlf_ = jrb >> 4;
  const int vcol0 = ((t_ >> 2) << 3) + (t_ & 3) + 4 * hlf_;  // + c*32
  const unsigned short* kvb = KV + ((size_t)bt * CNK) * 2048 + h * 64 + seg * 8;

  uint4 kk[2], vv[2];
  auto load_tile = [&](int j0) {
#pragma unroll
    for (int c = 0; c < 2; ++c) {
      const int j = j0 + c * 32 + jrb;
      if (j < CNK) {
        const unsigned short* p = kvb + (size_t)j * 2048;
        kk[c] = *(const uint4*)p;
        vv[c] = *(const uint4*)(p + 1024);
      } else {
        kk[c] = make_uint4(0, 0, 0, 0);
        vv[c] = make_uint4(0, 0, 0, 0);
      }
    }
  };
  auto write_tile = [&](int buf) {
#pragma unroll
    for (int c = 0; c < 2; ++c) {
      const int jr = c * 32 + jrb;
      *(uint4*)&ks[buf][jr * 72 + seg * 8] = kk[c];
      const int vcol = c * 32 + vcol0;
      const unsigned int w[4] = {vv[c].x, vv[c].y, vv[c].z, vv[c].w};
#pragma unroll
      for (int p = 0; p < 4; ++p) {
        vt[buf][(seg * 8 + 2 * p + 0) * 72 + vcol] = (unsigned short)(w[p] & 0xffffu);
        vt[buf][(seg * 8 + 2 * p + 1) * 72 + vcol] = (unsigned short)(w[p] >> 16);
      }
    }
  };

  float l = 0.f;
  floatx4 O[4] = {{0,0,0,0}, {0,0,0,0}, {0,0,0,0}, {0,0,0,0}};
  const float expC = 0.18033688011112042f;  // 0.125 * log2(e)

  load_tile(0);
  write_tile(0);
  constexpr int NT = 17;  // ceil(1025/64)
  for (int t = 0; t < NT; ++t) {
    if (t + 1 < NT) load_tile((t + 1) * 64);
    __syncthreads();
    const int buf = t & 1;
    const unsigned short* ksb = ks[buf];
    const unsigned short* vtb = vt[buf];
#pragma unroll
    for (int c = 0; c < 2; ++c) {
      floatx4 s0 = {0,0,0,0}, s1 = {0,0,0,0};
      const short8 a00 = *(const short8*)&ksb[((2*c)   * 16 + i16) * 72 + quad * 8];
      const short8 a01 = *(const short8*)&ksb[((2*c)   * 16 + i16) * 72 + 32 + quad * 8];
      const short8 a10 = *(const short8*)&ksb[((2*c+1) * 16 + i16) * 72 + quad * 8];
      const short8 a11 = *(const short8*)&ksb[((2*c+1) * 16 + i16) * 72 + 32 + quad * 8];
      s0 = mfma_bf16(a00, bq0, s0); s0 = mfma_bf16(a01, bq1, s0);
      s1 = mfma_bf16(a10, bq0, s1); s1 = mfma_bf16(a11, bq1, s1);
      unsigned short pb0[4], pb1[4];
      if (t == NT - 1) {  // masked tail tile (keys 1024..1087; only 1024 valid)
#pragma unroll
        for (int r = 0; r < 4; ++r) {
          const int k0g = t * 64 + (2*c)   * 16 + quad * 4 + r;
          const int k1g = t * 64 + (2*c+1) * 16 + quad * 4 + r;
          const float p0 = (k0g < CNK) ? exp2f(s0[r] * expC) : 0.f;
          const float p1 = (k1g < CNK) ? exp2f(s1[r] * expC) : 0.f;
          l += p0 + p1;
          pb0[r] = f2bf(p0); pb1[r] = f2bf(p1);
        }
      } else {
#pragma unroll
        for (int r = 0; r < 4; ++r) {
          const float p0 = exp2f(s0[r] * expC);
          const float p1 = exp2f(s1[r] * expC);
          l += p0 + p1;
          pb0[r] = f2bf(p0); pb1[r] = f2bf(p1);
        }
      }
      const short8 bp = {
          (short)pb0[0], (short)pb0[1], (short)pb0[2], (short)pb0[3],
          (short)pb1[0], (short)pb1[1], (short)pb1[2], (short)pb1[3]};
#pragma unroll
      for (int dt = 0; dt < 4; ++dt) {
        const short8 av = *(const short8*)&vtb[(dt * 16 + i16) * 72 + c * 32 + quad * 8];
        O[dt] = mfma_bf16(av, bp, O[dt]);
      }
    }
    if (t + 1 < NT) write_tile((t + 1) & 1);
  }

  l += __shfl_xor(l, 16);
  l += __shfl_xor(l, 32);
  const float wsc = dw[bt * 16 + h] / l;
  unsigned short* obase = AO + ((size_t)(bt * 64 + wrow + i16)) * CINNER + h * 64;
#pragma unroll
  for (int dt = 0; dt < 4; ++dt)
#pragma unroll
    for (int r = 0; r < 4; ++r)
      obase[dt * 16 + quad * 4 + r] = f2bf(O[dt][r] * wsc);
}

// ---------- host ----------
extern "C" void kernel_launch(void* const* d_in, const int* in_sizes, int n_in,
                              void* d_out, int out_size, void* d_ws, size_t ws_size,
                              hipStream_t stream) {
  const float* x       = (const float*)d_in[0];
  const float* latents = (const float*)d_in[1];
  const float* gm  = (const float*)d_in[2];
  const float* bm  = (const float*)d_in[3];
  const float* gl  = (const float*)d_in[4];
  const float* bl  = (const float*)d_in[5];
  const float* Wq  = (const float*)d_in[6];
  const float* Wkv = (const float*)d_in[7];
  const float* Wout= (const float*)d_in[8];
  const float* Wd1 = (const float*)d_in[9];
  const float* bd1 = (const float*)d_in[10];
  const float* Wd2 = (const float*)d_in[11];
  const float* bd2 = (const float*)d_in[12];
  float* out = (float*)d_out;

  char* ws = (char*)d_ws;
  size_t off = 0;
  auto alloc = [&](size_t bytes) -> void* {
    void* p = ws + off;
    off += (bytes + 255) & ~(size_t)255;
    return p;
  };
  unsigned short* xn   = (unsigned short*)alloc((size_t)CBT * CN1 * CD * 2);      // 64 MB
  unsigned short* kv   = (unsigned short*)alloc((size_t)CBT * CNK * 2048 * 2);    // 131 MB
  float*          lnf  = (float*)        alloc((size_t)CBT * CN2 * CD * 4);       // 8 MB
  unsigned short* lnb  = (unsigned short*)alloc((size_t)CBT * CN2 * CD * 2);      // 4 MB
  unsigned short* wqT  = (unsigned short*)alloc((size_t)CD * CINNER * 2);         // 2 MB  [N][K]
  unsigned short* wkvT = (unsigned short*)alloc((size_t)CD * 2 * CINNER * 2);     // 4 MB  [2N][K]
  unsigned short* woT  = (unsigned short*)alloc((size_t)CINNER * CD * 2);         // 2 MB  [N][K]
  unsigned short* qb   = (unsigned short*)alloc((size_t)CBT * CN2 * CINNER * 2);  // 4 MB
  unsigned short* aob  = (unsigned short*)alloc((size_t)CBT * CN2 * CINNER * 2);  // 4 MB
  float*          dwp  = (float*)        alloc((size_t)CBT * CH * 4);
  float*          meanp= (float*)        alloc((size_t)CBT * CD * 4);             // 128 KB
  float*          hidp = (float*)        alloc((size_t)CBT * 256 * 4);            // 32 KB
  if (off > ws_size) return;  // signal: output stays zero (ws too small)

  // 1) layernorms (x -> bf16; latents -> bf16 + fp32)
  ln_kernel<<<CBT * CN1 / 4, 256, 0, stream>>>(x, gm, bm, xn, nullptr);
  ln_kernel<<<CBT * CN2 / 4, 256, 0, stream>>>(latents, gl, bl, lnb, lnf);
  // 2) weight transpose + bf16 convert: W[K][N] -> WT[N][K]
  wtrans_kernel<<<dim3(CINNER / 64, CD / 64), 256, 0, stream>>>(Wq, wqT, CD, CINNER);
  wtrans_kernel<<<dim3(2 * CINNER / 64, CD / 64), 256, 0, stream>>>(Wkv, wkvT, CD, 2 * CINNER);
  wtrans_kernel<<<dim3(CD / 64, CINNER / 64), 256, 0, stream>>>(Wout, woT, CINNER, CD);
  // 3) Q = ln @ Wq   (2048 x 1024 x 1024)
  gemm128_kernel<false, true><<<dim3(1024 / 128, 2048 / 128), 256, 0, stream>>>(
      lnb, nullptr, nullptr, wqT, qb, nullptr, 2048, 1024, 1024);
  // 4) KV = concat(xn, ln[:, :, 0:1]) @ Wkv   (32800 x 2048 x 1024)
  //    128^2-tile, 4-wave, 3-slot counted-vmcnt ring, 3 blocks/CU.
  {
    const int MB = (CBT * CNK + 127) / 128;   // 257
    gemmkv_kernel<true><<<MB * 16, 256, 0, stream>>>(
        xn, lnb, wkvT, kv, CBT * CNK, 2048, 1024, 16);
  }
  // 5) dynamic head weights (3-stage, parallel)
  dwmean_kernel<<<CBT * 4, 256, 0, stream>>>(lnf, meanp);
  dwmlp_kernel<<<CBT * 8, 256, 0, stream>>>(meanp, Wd1, bd1, hidp);
  dwfin_kernel<<<CBT, 256, 0, stream>>>(hidp, Wd2, bd2, dwp);
  // 6) attention (512 blocks = BT * H, XCD-grouped by bt)
  attn_kernel<<<CBT * CH, 256, 0, stream>>>(qb, kv, dwp, aob);
  // 7) out = AO @ Wout   (2048 x 1024 x 1024) -> fp32 d_out
  gemm128_kernel<false, false><<<dim3(1024 / 128, 2048 / 128), 256, 0, stream>>>(
      aob, nullptr, nullptr, woT, nullptr, out, 2048, 1024, 1024);
}